// Round 1
// baseline (10692.700 us; speedup 1.0000x reference)
//
#include <hip/hip_runtime.h>

// Problem constants (shapes fixed by the reference).
constexpr float EPS = 1e-5f;

// ---------------------------------------------------------------------------
// K1: h[n,256] = x[n,256] @ Wl[p][256,64] (+ bl), all 4 paths as one GEMM.
// h column layout = p*64 + d  (matches cat order).
// Tile 64x64, block 256 threads (16x16), 4x4 microtile, K-chunk 16.
// ---------------------------------------------------------------------------
__global__ __launch_bounds__(256) void k1_gemm_h(
    const float* __restrict__ x, const float* __restrict__ Wl,
    const float* __restrict__ bl, float* __restrict__ h, int n)
{
    __shared__ float As[16][68];   // [k][m], pad 68 -> conflict-free stores
    __shared__ float Bs[16][64];   // [k][n]
    const int row0 = blockIdx.x * 64;
    const int pb   = blockIdx.y;           // path (column block)
    const int t    = threadIdx.x;
    const int tx = t & 15, ty = t >> 4;
    const int ka = t & 15, ma = t >> 4;    // A-load coords
    const int nb = t & 63, kb = t >> 6;    // B-load coords
    const float* Wp = Wl + (size_t)pb * 256 * 64;
    float acc[4][4] = {};

    for (int k0 = 0; k0 < 256; k0 += 16) {
        #pragma unroll
        for (int i = 0; i < 4; i++)
            As[ka][ma + 16 * i] = x[(size_t)(row0 + ma + 16 * i) * 256 + k0 + ka];
        #pragma unroll
        for (int i = 0; i < 4; i++)
            Bs[kb + 4 * i][nb] = Wp[(size_t)(k0 + kb + 4 * i) * 64 + nb];
        __syncthreads();
        #pragma unroll
        for (int kk = 0; kk < 16; kk++) {
            float a[4], b[4];
            #pragma unroll
            for (int i = 0; i < 4; i++) a[i] = As[kk][ty * 4 + i];
            #pragma unroll
            for (int j = 0; j < 4; j++) b[j] = Bs[kk][tx * 4 + j];
            #pragma unroll
            for (int i = 0; i < 4; i++)
                #pragma unroll
                for (int j = 0; j < 4; j++)
                    acc[i][j] += a[i] * b[j];
        }
        __syncthreads();
    }
    #pragma unroll
    for (int i = 0; i < 4; i++) {
        const int r = row0 + ty * 4 + i;
        #pragma unroll
        for (int j = 0; j < 4; j++) {
            const int c = pb * 64 + tx * 4 + j;
            h[(size_t)r * 256 + c] = acc[i][j] + bl[c];
        }
    }
}

// ---------------------------------------------------------------------------
// K2: gather-matmul-scatter conv. Block = (p, k, 64-pair chunk).
// C[m,d] = sum_c h[j_m, p*64+c] * Wc[p,k,c,d]; atomicAdd into accum[i_m, p*64+d].
// Sentinel index == n marks padded pairs (skip).
// ---------------------------------------------------------------------------
__global__ __launch_bounds__(256) void k2_conv(
    const float* __restrict__ h, const float* __restrict__ Wc,
    const int* __restrict__ in_idx, const int* __restrict__ out_idx,
    float* __restrict__ accum, int n, int M)
{
    __shared__ float Ws[64][64];   // Wc[p][k]: [c][d]
    __shared__ float G[64][65];    // gathered h rows: [m][c], pad 65
    __shared__ int jj[64], ii[64];

    const int p  = blockIdx.z;
    const int k  = blockIdx.y;
    const int m0 = blockIdx.x * 64;
    const int t  = threadIdx.x;
    const int base = (p * 27 + k) * M;

    // Padding fills the tail of each (p,k) row: if first pair of the chunk is
    // sentinel, all 64 are -> whole block exits (uniform).
    if (in_idx[base + m0] >= n) return;

    const float* Wp = Wc + (size_t)(p * 27 + k) * 4096;
    #pragma unroll
    for (int i = 0; i < 16; i++)
        ((float*)Ws)[t + 256 * i] = Wp[t + 256 * i];
    if (t < 64) {
        jj[t] = in_idx[base + m0 + t];
        ii[t] = out_idx[base + m0 + t];
    }
    __syncthreads();

    // Gather 64 rows x 64 channels of h (coalesced 256B rows).
    {
        const int c = t & 63;
        const int mr = t >> 6;
        #pragma unroll
        for (int i = 0; i < 16; i++) {
            const int m = mr + 4 * i;
            const int j = jj[m];
            G[m][c] = (j < n) ? h[(size_t)j * 256 + p * 64 + c] : 0.0f;
        }
    }
    __syncthreads();

    // Thread = (pair m, 16-channel group).
    const int m  = t >> 2;
    const int c0 = (t & 3) * 16;
    float acc[16] = {};
    #pragma unroll
    for (int kk = 0; kk < 64; kk++) {
        const float a = G[m][kk];
        #pragma unroll
        for (int j = 0; j < 16; j++)
            acc[j] += a * Ws[kk][c0 + j];
    }
    const int i = ii[m];
    if (i < n) {
        float* dst = accum + (size_t)i * 256 + p * 64 + c0;
        #pragma unroll
        for (int j = 0; j < 16; j++)
            atomicAdd(dst + j, acc[j]);
    }
}

// ---------------------------------------------------------------------------
// K3a: per-column sum / sumsq over accum[n,256].
// ---------------------------------------------------------------------------
__global__ __launch_bounds__(256) void k3_stats(
    const float* __restrict__ acc, float* __restrict__ ssum,
    float* __restrict__ ssq, int n)
{
    const int t = threadIdx.x;
    float s = 0.f, s2 = 0.f;
    for (int r = blockIdx.x; r < n; r += gridDim.x) {
        const float v = acc[(size_t)r * 256 + t];
        s += v;
        s2 += v * v;
    }
    atomicAdd(&ssum[t], s);
    atomicAdd(&ssq[t], s2);
}

// K3b: fold stats into affine scale/shift per column.
__global__ void k3_final(
    const float* __restrict__ ssum, const float* __restrict__ ssq,
    const float* __restrict__ gamma, const float* __restrict__ beta,
    float* __restrict__ scale, float* __restrict__ shift, int n)
{
    const int t = threadIdx.x;  // 256
    const float inv_n = 1.0f / (float)n;
    const float mu  = ssum[t] * inv_n;
    const float var = ssq[t] * inv_n - mu * mu;
    const float sc  = gamma[t] * rsqrtf(var + EPS);
    scale[t] = sc;
    shift[t] = beta[t] - mu * sc;
}

// ---------------------------------------------------------------------------
// K4: out[n,256] = relu(accum*scale+shift) @ W2 + b2 + x   (BN fused in A-load)
// Same tiling as K1.
// ---------------------------------------------------------------------------
__global__ __launch_bounds__(256) void k4_gemm_out(
    const float* __restrict__ acc_in, const float* __restrict__ W2,
    const float* __restrict__ b2, const float* __restrict__ x,
    const float* __restrict__ scale, const float* __restrict__ shift,
    float* __restrict__ out, int n)
{
    __shared__ float As[16][68];
    __shared__ float Bs[16][64];
    __shared__ float sc[256], sh[256];
    const int row0 = blockIdx.x * 64;
    const int col0 = blockIdx.y * 64;
    const int t = threadIdx.x;
    const int tx = t & 15, ty = t >> 4;
    const int ka = t & 15, ma = t >> 4;
    const int nb = t & 63, kb = t >> 6;
    float acc[4][4] = {};

    sc[t] = scale[t];
    sh[t] = shift[t];
    __syncthreads();

    for (int k0 = 0; k0 < 256; k0 += 16) {
        const float s_k = sc[k0 + ka];
        const float h_k = sh[k0 + ka];
        #pragma unroll
        for (int i = 0; i < 4; i++) {
            float v = acc_in[(size_t)(row0 + ma + 16 * i) * 256 + k0 + ka];
            v = v * s_k + h_k;
            As[ka][ma + 16 * i] = fmaxf(v, 0.0f);
        }
        #pragma unroll
        for (int i = 0; i < 4; i++)
            Bs[kb + 4 * i][nb] = W2[(size_t)(k0 + kb + 4 * i) * 256 + col0 + nb];
        __syncthreads();
        #pragma unroll
        for (int kk = 0; kk < 16; kk++) {
            float a[4], b[4];
            #pragma unroll
            for (int i = 0; i < 4; i++) a[i] = As[kk][ty * 4 + i];
            #pragma unroll
            for (int j = 0; j < 4; j++) b[j] = Bs[kk][tx * 4 + j];
            #pragma unroll
            for (int i = 0; i < 4; i++)
                #pragma unroll
                for (int j = 0; j < 4; j++)
                    acc[i][j] += a[i] * b[j];
        }
        __syncthreads();
    }
    #pragma unroll
    for (int i = 0; i < 4; i++) {
        const int r = row0 + ty * 4 + i;
        #pragma unroll
        for (int j = 0; j < 4; j++) {
            const int c = col0 + tx * 4 + j;
            out[(size_t)r * 256 + c] = acc[i][j] + b2[c] + x[(size_t)r * 256 + c];
        }
    }
}

// ---------------------------------------------------------------------------
extern "C" void kernel_launch(void* const* d_in, const int* in_sizes, int n_in,
                              void* d_out, int out_size, void* d_ws, size_t ws_size,
                              hipStream_t stream)
{
    const float* x     = (const float*)d_in[0];
    const float* Wl    = (const float*)d_in[1];
    const float* bl    = (const float*)d_in[2];
    const float* Wc    = (const float*)d_in[3];
    const float* gamma = (const float*)d_in[4];
    const float* beta  = (const float*)d_in[5];
    const float* W2    = (const float*)d_in[6];
    const float* b2    = (const float*)d_in[7];
    const int* in_idx  = (const int*)d_in[8];
    const int* out_idx = (const int*)d_in[9];

    const int n = in_sizes[0] / 256;        // 200000
    const int M = in_sizes[8] / (4 * 27);   // max pairs per (p,k)

    float* accum = (float*)d_out;                       // conv accumulator = d_out
    float* h     = (float*)d_ws;                        // [n,256] fp32
    const size_t hbytes = (size_t)n * 256 * sizeof(float);
    float* stats = (float*)((char*)d_ws + hbytes);
    float* ssum = stats, *ssq = stats + 256;
    float* scalev = stats + 512, *shiftv = stats + 768;
    float* result = h;                                  // reuse h region for K4 output

    // Zero the accumulator (d_out is poisoned 0xAA each call) and the stats.
    hipMemsetAsync(d_out, 0, hbytes, stream);
    hipMemsetAsync(stats, 0, 512 * sizeof(float), stream);

    const int rb = n / 64;  // 3125 (n = 200000 divides by 64 exactly)

    dim3 g1(rb, 4);
    k1_gemm_h<<<g1, 256, 0, stream>>>(x, Wl, bl, h, n);

    dim3 g2((M + 63) / 64, 27, 4);
    k2_conv<<<g2, 256, 0, stream>>>(h, Wc, in_idx, out_idx, accum, n, M);

    k3_stats<<<512, 256, 0, stream>>>(accum, ssum, ssq, n);
    k3_final<<<1, 256, 0, stream>>>(ssum, ssq, gamma, beta, scalev, shiftv, n);

    dim3 g4(rb, 4);
    k4_gemm_out<<<g4, 256, 0, stream>>>(accum, W2, b2, x, scalev, shiftv, result, n);

    hipMemcpyAsync(d_out, result, hbytes, hipMemcpyDeviceToDevice, stream);
}

// Round 2
// 3212.045 us; speedup vs baseline: 3.3289x; 3.3289x over previous
//
#include <hip/hip_runtime.h>

constexpr float EPS = 1e-5f;

// ---------------------------------------------------------------------------
// K1: h[n,256] = x[n,256] @ Wl[p][256,64] (+ bl), all 4 paths as one GEMM.
// ---------------------------------------------------------------------------
__global__ __launch_bounds__(256) void k1_gemm_h(
    const float* __restrict__ x, const float* __restrict__ Wl,
    const float* __restrict__ bl, float* __restrict__ h, int n)
{
    __shared__ float As[16][68];
    __shared__ float Bs[16][64];
    const int row0 = blockIdx.x * 64;
    const int pb   = blockIdx.y;
    const int t    = threadIdx.x;
    const int tx = t & 15, ty = t >> 4;
    const int ka = t & 15, ma = t >> 4;
    const int nb = t & 63, kb = t >> 6;
    const float* Wp = Wl + (size_t)pb * 256 * 64;
    float acc[4][4] = {};

    for (int k0 = 0; k0 < 256; k0 += 16) {
        #pragma unroll
        for (int i = 0; i < 4; i++)
            As[ka][ma + 16 * i] = x[(size_t)(row0 + ma + 16 * i) * 256 + k0 + ka];
        #pragma unroll
        for (int i = 0; i < 4; i++)
            Bs[kb + 4 * i][nb] = Wp[(size_t)(k0 + kb + 4 * i) * 64 + nb];
        __syncthreads();
        #pragma unroll
        for (int kk = 0; kk < 16; kk++) {
            float a[4], b[4];
            #pragma unroll
            for (int i = 0; i < 4; i++) a[i] = As[kk][ty * 4 + i];
            #pragma unroll
            for (int j = 0; j < 4; j++) b[j] = Bs[kk][tx * 4 + j];
            #pragma unroll
            for (int i = 0; i < 4; i++)
                #pragma unroll
                for (int j = 0; j < 4; j++)
                    acc[i][j] += a[i] * b[j];
        }
        __syncthreads();
    }
    #pragma unroll
    for (int i = 0; i < 4; i++) {
        const int r = row0 + ty * 4 + i;
        #pragma unroll
        for (int j = 0; j < 4; j++) {
            const int c = pb * 64 + tx * 4 + j;
            h[(size_t)r * 256 + c] = acc[i][j] + bl[c];
        }
    }
}

// ---------------------------------------------------------------------------
// K2: output-centric gather conv — NO atomics.
// Block = (64 output rows, path p). out_idx[p][k] is sorted ascending with
// sentinel-n tail, so each k's contributions to this row range are one
// contiguous run found by binary search. Compacted MAC per k accumulates
// into an LDS 64x64 tile; single streaming write at the end (full coverage,
// so d_out needs no zero-init).
// Wave-rotated row assignment (mrow group ^= k) balances the ~6-valid-rows
// case across the block's 4 waves.
// ---------------------------------------------------------------------------
__global__ __launch_bounds__(256) void k2_conv(
    const float* __restrict__ h, const float* __restrict__ Wc,
    const int* __restrict__ in_idx, const int* __restrict__ out_idx,
    float* __restrict__ accum, int n, int M)
{
    __shared__ float Ws[64][64];   // Wc[p][k]: [c][d]
    __shared__ float G[64][68];    // compacted gathered h rows (stride 68: 16B-aligned rows, 2-way-max banks)
    __shared__ float Acc[64][68];  // output tile accumulator
    __shared__ int csrc[64];
    __shared__ int cdst[64];
    __shared__ int spos[27];
    __shared__ int nv_s;

    const int p    = blockIdx.y;
    const int row0 = blockIdx.x * 64;
    const int t    = threadIdx.x;
    const int hcol = p * 64;

    for (int i = t; i < 64 * 68; i += 256) ((float*)Acc)[i] = 0.0f;

    // lower_bound(row0) in each of the 27 sorted out_idx lists.
    if (t < 27) {
        const int* oi = out_idx + (size_t)(p * 27 + t) * M;
        int lo = 0, hi = M;
        while (lo < hi) {
            const int mid = (lo + hi) >> 1;
            if (oi[mid] < row0) lo = mid + 1; else hi = mid;
        }
        spos[t] = lo;
    }
    __syncthreads();

    const int lane16 = (t & 63) >> 2;   // 0..15
    const int c0     = (t & 3) << 4;    // channel group
    const int wv     = t >> 6;          // wave id

    for (int k = 0; k < 27; k++) {
        const size_t base = (size_t)(p * 27 + k) * M;

        // wave 0: compaction (valid entries are a contiguous prefix -> index = t)
        if (t < 64) {
            const int pos   = spos[k] + t;
            const int o     = (pos < M) ? out_idx[base + pos] : n;
            const bool valid = (o < row0 + 64);
            const unsigned long long mask = __ballot(valid);
            if (valid) { csrc[t] = in_idx[base + pos]; cdst[t] = o - row0; }
            if (t == 0) nv_s = (int)__popcll(mask);
        }
        // all threads: stage Wc[p][k] (16 KB) as float4
        {
            const float4* Wp4 = (const float4*)(Wc + (size_t)(p * 27 + k) * 4096);
            const float4 w0 = Wp4[t], w1 = Wp4[t + 256], w2 = Wp4[t + 512], w3 = Wp4[t + 768];
            ((float4*)Ws)[t] = w0;
            ((float4*)Ws)[t + 256] = w1;
            ((float4*)Ws)[t + 512] = w2;
            ((float4*)Ws)[t + 768] = w3;
        }
        __syncthreads();
        const int nv = nv_s;

        // gather compacted h rows (16 threads/row, float4-coalesced)
        for (int r = t >> 4; r < nv; r += 16) {
            const float4 v = *(const float4*)(h + (size_t)csrc[r] * 256 + hcol + ((t & 15) << 2));
            *(float4*)&G[r][(t & 15) << 2] = v;
        }
        __syncthreads();

        // compacted MAC: row assignment rotated by k across waves
        const int mrow = (((wv + k) & 3) << 4) + lane16;
        if (mrow < nv) {
            float acc[16] = {};
            #pragma unroll
            for (int c = 0; c < 64; c++) {
                const float a = G[mrow][c];
                #pragma unroll
                for (int j = 0; j < 16; j++) acc[j] += a * Ws[c][c0 + j];
            }
            const int d = cdst[mrow];
            #pragma unroll
            for (int j = 0; j < 16; j++) Acc[d][c0 + j] += acc[j];
        }
        __syncthreads();
    }

    // streaming write of the block's 64x64 patch (written exactly once)
    for (int i = t; i < 64 * 16; i += 256) {
        const int r = i >> 4, cc = (i & 15) << 2;
        *(float4*)(accum + (size_t)(row0 + r) * 256 + hcol + cc) = *(const float4*)&Acc[r][cc];
    }
}

// ---------------------------------------------------------------------------
// K3a: per-column sum / sumsq over accum[n,256].
// ---------------------------------------------------------------------------
__global__ __launch_bounds__(256) void k3_stats(
    const float* __restrict__ acc, float* __restrict__ ssum,
    float* __restrict__ ssq, int n)
{
    const int t = threadIdx.x;
    float s = 0.f, s2 = 0.f;
    for (int r = blockIdx.x; r < n; r += gridDim.x) {
        const float v = acc[(size_t)r * 256 + t];
        s += v;
        s2 += v * v;
    }
    atomicAdd(&ssum[t], s);
    atomicAdd(&ssq[t], s2);
}

__global__ void k3_final(
    const float* __restrict__ ssum, const float* __restrict__ ssq,
    const float* __restrict__ gamma, const float* __restrict__ beta,
    float* __restrict__ scale, float* __restrict__ shift, int n)
{
    const int t = threadIdx.x;  // 256
    const float inv_n = 1.0f / (float)n;
    const float mu  = ssum[t] * inv_n;
    const float var = ssq[t] * inv_n - mu * mu;
    const float sc  = gamma[t] * rsqrtf(var + EPS);
    scale[t] = sc;
    shift[t] = beta[t] - mu * sc;
}

// ---------------------------------------------------------------------------
// K4: out[n,256] = relu(accum*scale+shift) @ W2 + b2 + x   (BN fused in A-load)
// ---------------------------------------------------------------------------
__global__ __launch_bounds__(256) void k4_gemm_out(
    const float* __restrict__ acc_in, const float* __restrict__ W2,
    const float* __restrict__ b2, const float* __restrict__ x,
    const float* __restrict__ scale, const float* __restrict__ shift,
    float* __restrict__ out, int n)
{
    __shared__ float As[16][68];
    __shared__ float Bs[16][64];
    __shared__ float sc[256], sh[256];
    const int row0 = blockIdx.x * 64;
    const int col0 = blockIdx.y * 64;
    const int t = threadIdx.x;
    const int tx = t & 15, ty = t >> 4;
    const int ka = t & 15, ma = t >> 4;
    const int nb = t & 63, kb = t >> 6;
    float acc[4][4] = {};

    sc[t] = scale[t];
    sh[t] = shift[t];
    __syncthreads();

    for (int k0 = 0; k0 < 256; k0 += 16) {
        const float s_k = sc[k0 + ka];
        const float h_k = sh[k0 + ka];
        #pragma unroll
        for (int i = 0; i < 4; i++) {
            float v = acc_in[(size_t)(row0 + ma + 16 * i) * 256 + k0 + ka];
            v = v * s_k + h_k;
            As[ka][ma + 16 * i] = fmaxf(v, 0.0f);
        }
        #pragma unroll
        for (int i = 0; i < 4; i++)
            Bs[kb + 4 * i][nb] = W2[(size_t)(k0 + kb + 4 * i) * 256 + col0 + nb];
        __syncthreads();
        #pragma unroll
        for (int kk = 0; kk < 16; kk++) {
            float a[4], b[4];
            #pragma unroll
            for (int i = 0; i < 4; i++) a[i] = As[kk][ty * 4 + i];
            #pragma unroll
            for (int j = 0; j < 4; j++) b[j] = Bs[kk][tx * 4 + j];
            #pragma unroll
            for (int i = 0; i < 4; i++)
                #pragma unroll
                for (int j = 0; j < 4; j++)
                    acc[i][j] += a[i] * b[j];
        }
        __syncthreads();
    }
    #pragma unroll
    for (int i = 0; i < 4; i++) {
        const int r = row0 + ty * 4 + i;
        #pragma unroll
        for (int j = 0; j < 4; j++) {
            const int c = col0 + tx * 4 + j;
            out[(size_t)r * 256 + c] = acc[i][j] + b2[c] + x[(size_t)r * 256 + c];
        }
    }
}

// ---------------------------------------------------------------------------
extern "C" void kernel_launch(void* const* d_in, const int* in_sizes, int n_in,
                              void* d_out, int out_size, void* d_ws, size_t ws_size,
                              hipStream_t stream)
{
    const float* x     = (const float*)d_in[0];
    const float* Wl    = (const float*)d_in[1];
    const float* bl    = (const float*)d_in[2];
    const float* Wc    = (const float*)d_in[3];
    const float* gamma = (const float*)d_in[4];
    const float* beta  = (const float*)d_in[5];
    const float* W2    = (const float*)d_in[6];
    const float* b2    = (const float*)d_in[7];
    const int* in_idx  = (const int*)d_in[8];
    const int* out_idx = (const int*)d_in[9];

    const int n = in_sizes[0] / 256;        // 200000
    const int M = in_sizes[8] / (4 * 27);   // max pairs per (p,k)

    float* accum = (float*)d_out;                       // conv accumulator = d_out (fully overwritten by k2)
    float* h     = (float*)d_ws;                        // [n,256] fp32
    const size_t hbytes = (size_t)n * 256 * sizeof(float);
    float* stats = (float*)((char*)d_ws + hbytes);
    float* ssum = stats, *ssq = stats + 256;
    float* scalev = stats + 512, *shiftv = stats + 768;
    float* result = h;                                  // reuse h region for K4 output

    hipMemsetAsync(stats, 0, 512 * sizeof(float), stream);

    const int rb = n / 64;  // 3125

    dim3 g1(rb, 4);
    k1_gemm_h<<<g1, 256, 0, stream>>>(x, Wl, bl, h, n);

    dim3 g2(rb, 4);
    k2_conv<<<g2, 256, 0, stream>>>(h, Wc, in_idx, out_idx, accum, n, M);

    k3_stats<<<512, 256, 0, stream>>>(accum, ssum, ssq, n);
    k3_final<<<1, 256, 0, stream>>>(ssum, ssq, gamma, beta, scalev, shiftv, n);

    dim3 g4(rb, 4);
    k4_gemm_out<<<g4, 256, 0, stream>>>(accum, W2, b2, x, scalev, shiftv, result, n);

    hipMemcpyAsync(d_out, result, hbytes, hipMemcpyDeviceToDevice, stream);
}

// Round 3
// 2321.678 us; speedup vs baseline: 4.6056x; 1.3835x over previous
//
#include <hip/hip_runtime.h>
#include <hip/hip_bf16.h>

constexpr float EPS = 1e-5f;

typedef __attribute__((ext_vector_type(8))) short short8;   // 8 bf16 = 4 VGPRs
typedef __attribute__((ext_vector_type(4))) float floatx4;  // MFMA C/D

// ---------------------------------------------------------------------------
// K1: h[n,256](bf16) = x[n,256] @ Wl[p][256,64] (+ bl). fp32 VALU GEMM,
// bf16 output (only k2 consumes h).
// ---------------------------------------------------------------------------
__global__ __launch_bounds__(256) void k1_gemm_h(
    const float* __restrict__ x, const float* __restrict__ Wl,
    const float* __restrict__ bl, __hip_bfloat16* __restrict__ hb, int n)
{
    __shared__ float As[16][68];
    __shared__ float Bs[16][64];
    const int row0 = blockIdx.x * 64;
    const int pb   = blockIdx.y;
    const int t    = threadIdx.x;
    const int tx = t & 15, ty = t >> 4;
    const int ka = t & 15, ma = t >> 4;
    const int nb = t & 63, kb = t >> 6;
    const float* Wp = Wl + (size_t)pb * 256 * 64;
    float acc[4][4] = {};

    for (int k0 = 0; k0 < 256; k0 += 16) {
        #pragma unroll
        for (int i = 0; i < 4; i++)
            As[ka][ma + 16 * i] = x[(size_t)(row0 + ma + 16 * i) * 256 + k0 + ka];
        #pragma unroll
        for (int i = 0; i < 4; i++)
            Bs[kb + 4 * i][nb] = Wp[(size_t)(k0 + kb + 4 * i) * 64 + nb];
        __syncthreads();
        #pragma unroll
        for (int kk = 0; kk < 16; kk++) {
            float a[4], b[4];
            #pragma unroll
            for (int i = 0; i < 4; i++) a[i] = As[kk][ty * 4 + i];
            #pragma unroll
            for (int j = 0; j < 4; j++) b[j] = Bs[kk][tx * 4 + j];
            #pragma unroll
            for (int i = 0; i < 4; i++)
                #pragma unroll
                for (int j = 0; j < 4; j++)
                    acc[i][j] += a[i] * b[j];
        }
        __syncthreads();
    }
    #pragma unroll
    for (int i = 0; i < 4; i++) {
        const int r = row0 + ty * 4 + i;
        #pragma unroll
        for (int j = 0; j < 4; j++) {
            const int c = pb * 64 + tx * 4 + j;
            hb[(size_t)r * 256 + c] = __float2bfloat16(acc[i][j] + bl[c]);
        }
    }
}

// ---------------------------------------------------------------------------
// K2: output-centric gather conv, bf16 MFMA MAC, no atomics.
// Block = (p, 64 output rows). Per k: wave0 compacts the sorted out_idx run,
// waves1-3 transpose-stage Wc[p][k] to bf16 WsT[d][cin]; gather bf16 h rows;
// MFMA 16x16x32 over up to 4x4 tiles (wave w owns column strip w -> all
// waves active even at nv<=16); scatter C into fp32 LDS Acc guarded m<nv.
// ---------------------------------------------------------------------------
__global__ __launch_bounds__(256) void k2_conv(
    const __hip_bfloat16* __restrict__ hb, const float* __restrict__ Wc,
    const int* __restrict__ in_idx, const int* __restrict__ out_idx,
    float* __restrict__ accum, int n, int M)
{
    __shared__ __hip_bfloat16 WsT[64][72];  // [d][cin] bf16 (pad 72)
    __shared__ __hip_bfloat16 G[64][72];    // compacted h rows [m][cin]
    __shared__ float Acc[64][68];           // output tile accumulator
    __shared__ int csrc[64];
    __shared__ int cdst[64];
    __shared__ int spos[27];
    __shared__ int nv_s;

    const int p    = blockIdx.y;
    const int row0 = blockIdx.x * 64;
    const int t    = threadIdx.x;
    const int hcol = p * 64;
    const int lane = t & 63;
    const int wv   = t >> 6;

    for (int i = t; i < 64 * 68; i += 256) ((float*)Acc)[i] = 0.0f;

    if (t < 27) {
        const int* oi = out_idx + (size_t)(p * 27 + t) * M;
        int lo = 0, hi = M;
        while (lo < hi) {
            const int mid = (lo + hi) >> 1;
            if (oi[mid] < row0) lo = mid + 1; else hi = mid;
        }
        spos[t] = lo;
    }
    __syncthreads();

    for (int k = 0; k < 27; k++) {
        const size_t base = (size_t)(p * 27 + k) * M;

        if (wv == 0) {
            // compaction: valid entries are a contiguous prefix (sorted list)
            const int pos = spos[k] + lane;
            const int o   = (pos < M) ? out_idx[base + pos] : n;
            const bool valid = (o < row0 + 64);
            const unsigned long long mask = __ballot(valid);
            if (valid) { csrc[lane] = in_idx[base + pos]; cdst[lane] = o - row0; }
            if (lane == 0) nv_s = (int)__popcll(mask);
        } else {
            // transpose-stage Wc[p][k] (fp32 [cin][d]) -> WsT[d][cin] bf16
            const float* Wp = Wc + base / M * 4096;  // (p*27+k)*4096
            const int u = t - 64;
            #pragma unroll
            for (int e = 0; e < 22; e++) {
                const int idx = u + 192 * e;
                if (idx < 4096) {
                    const int cin = idx >> 6, d = idx & 63;
                    WsT[d][cin] = __float2bfloat16(Wp[idx]);
                }
            }
        }
        __syncthreads();

        const int nv = nv_s;
        if (nv > 0) {
            // gather compacted bf16 h rows: 8 threads/row, 16B each
            for (int r0 = t >> 3; r0 < nv; r0 += 32) {
                const uint4 v = *(const uint4*)(hb + (size_t)csrc[r0] * 256 + hcol + ((t & 7) << 3));
                *(uint4*)&G[r0][(t & 7) << 3] = v;
            }
            __syncthreads();

            const int TR   = (nv + 15) >> 4;   // tile rows 1..4
            const int mrow = lane & 15;        // = C/D col, A/B 16-index
            const int quad = lane >> 4;

            for (int tid = wv; tid < TR * 4; tid += 4) {
                const int tr = tid >> 2, tc = tid & 3;
                const short8 a0 = *(const short8*)&G[tr * 16 + mrow][quad * 8];
                const short8 a1 = *(const short8*)&G[tr * 16 + mrow][32 + quad * 8];
                const short8 b0 = *(const short8*)&WsT[tc * 16 + mrow][quad * 8];
                const short8 b1 = *(const short8*)&WsT[tc * 16 + mrow][32 + quad * 8];
                floatx4 acc = {0.f, 0.f, 0.f, 0.f};
                acc = __builtin_amdgcn_mfma_f32_16x16x32_bf16(a0, b0, acc, 0, 0, 0);
                acc = __builtin_amdgcn_mfma_f32_16x16x32_bf16(a1, b1, acc, 0, 0, 0);
                #pragma unroll
                for (int rg = 0; rg < 4; rg++) {
                    const int m = tr * 16 + quad * 4 + rg;  // C/D row
                    if (m < nv)
                        Acc[cdst[m]][tc * 16 + mrow] += acc[rg];
                }
            }
        }
        __syncthreads();  // Acc RMW done; G/WsT/csrc free for next k
    }

    // streaming write of the block's 64x64 patch (written exactly once)
    for (int i = t; i < 64 * 16; i += 256) {
        const int r = i >> 4, cc = (i & 15) << 2;
        *(float4*)(accum + (size_t)(row0 + r) * 256 + hcol + cc) = *(const float4*)&Acc[r][cc];
    }
}

// ---------------------------------------------------------------------------
// K3a: per-column sum / sumsq over accum[n,256].
// ---------------------------------------------------------------------------
__global__ __launch_bounds__(256) void k3_stats(
    const float* __restrict__ acc, float* __restrict__ ssum,
    float* __restrict__ ssq, int n)
{
    const int t = threadIdx.x;
    float s = 0.f, s2 = 0.f;
    for (int r = blockIdx.x; r < n; r += gridDim.x) {
        const float v = acc[(size_t)r * 256 + t];
        s += v;
        s2 += v * v;
    }
    atomicAdd(&ssum[t], s);
    atomicAdd(&ssq[t], s2);
}

__global__ void k3_final(
    const float* __restrict__ ssum, const float* __restrict__ ssq,
    const float* __restrict__ gamma, const float* __restrict__ beta,
    float* __restrict__ scale, float* __restrict__ shift, int n)
{
    const int t = threadIdx.x;  // 256
    const float inv_n = 1.0f / (float)n;
    const float mu  = ssum[t] * inv_n;
    const float var = ssq[t] * inv_n - mu * mu;
    const float sc  = gamma[t] * rsqrtf(var + EPS);
    scale[t] = sc;
    shift[t] = beta[t] - mu * sc;
}

// ---------------------------------------------------------------------------
// K4: io[n,256] = relu(io*scale+shift) @ W2 + b2 + x, IN-PLACE on d_out.
// Block = 64 full rows (all 256 cols): each block reads only its own rows,
// writes after all reads -> no cross-block hazard, no final copy.
// ---------------------------------------------------------------------------
__global__ __launch_bounds__(256) void k4_gemm_out(
    float* __restrict__ io, const float* __restrict__ W2,
    const float* __restrict__ b2, const float* __restrict__ x,
    const float* __restrict__ scale, const float* __restrict__ shift, int n)
{
    __shared__ float As[16][68];
    __shared__ float Bs[16][260];
    __shared__ float sc[256], sh[256];
    const int row0 = blockIdx.x * 64;
    const int t = threadIdx.x;
    const int tx = t & 15, ty = t >> 4;
    const int ka = t & 15, ma = t >> 4;
    float acc[4][16] = {};

    sc[t] = scale[t];
    sh[t] = shift[t];
    __syncthreads();

    for (int k0 = 0; k0 < 256; k0 += 16) {
        const float s_k = sc[k0 + ka];
        const float h_k = sh[k0 + ka];
        #pragma unroll
        for (int i = 0; i < 4; i++) {
            const float v = io[(size_t)(row0 + ma + 16 * i) * 256 + k0 + ka];
            As[ka][ma + 16 * i] = fmaxf(v * s_k + h_k, 0.0f);
        }
        #pragma unroll
        for (int r = 0; r < 16; r++)
            Bs[r][t] = W2[(size_t)(k0 + r) * 256 + t];
        __syncthreads();
        #pragma unroll
        for (int kk = 0; kk < 16; kk++) {
            float a[4], b[16];
            #pragma unroll
            for (int i = 0; i < 4; i++) a[i] = As[kk][ty * 4 + i];
            #pragma unroll
            for (int j = 0; j < 16; j++) b[j] = Bs[kk][j * 16 + tx];
            #pragma unroll
            for (int i = 0; i < 4; i++)
                #pragma unroll
                for (int j = 0; j < 16; j++)
                    acc[i][j] += a[i] * b[j];
        }
        __syncthreads();
    }
    // all global reads of io rows completed before this point (barrier-ordered)
    #pragma unroll
    for (int i = 0; i < 4; i++) {
        const size_t r = row0 + ty * 4 + i;
        #pragma unroll
        for (int j = 0; j < 16; j++) {
            const int c = j * 16 + tx;          // lanes consecutive -> coalesced
            io[r * 256 + c] = acc[i][j] + b2[c] + x[r * 256 + c];
        }
    }
}

// ---------------------------------------------------------------------------
extern "C" void kernel_launch(void* const* d_in, const int* in_sizes, int n_in,
                              void* d_out, int out_size, void* d_ws, size_t ws_size,
                              hipStream_t stream)
{
    const float* x     = (const float*)d_in[0];
    const float* Wl    = (const float*)d_in[1];
    const float* bl    = (const float*)d_in[2];
    const float* Wc    = (const float*)d_in[3];
    const float* gamma = (const float*)d_in[4];
    const float* beta  = (const float*)d_in[5];
    const float* W2    = (const float*)d_in[6];
    const float* b2    = (const float*)d_in[7];
    const int* in_idx  = (const int*)d_in[8];
    const int* out_idx = (const int*)d_in[9];

    const int n = in_sizes[0] / 256;        // 200000
    const int M = in_sizes[8] / (4 * 27);   // max pairs per (p,k)

    float* accum = (float*)d_out;           // conv accumulator = d_out (fully overwritten by k2)
    __hip_bfloat16* hb = (__hip_bfloat16*)d_ws;          // h bf16 [n,256]
    const size_t hb_bytes = (size_t)n * 256 * sizeof(__hip_bfloat16);
    float* stats = (float*)((char*)d_ws + hb_bytes);
    float* ssum = stats, *ssq = stats + 256;
    float* scalev = stats + 512, *shiftv = stats + 768;

    hipMemsetAsync(stats, 0, 512 * sizeof(float), stream);

    const int rb = n / 64;  // 3125

    dim3 g1(rb, 4);
    k1_gemm_h<<<g1, 256, 0, stream>>>(x, Wl, bl, hb, n);

    dim3 g2(rb, 4);
    k2_conv<<<g2, 256, 0, stream>>>(hb, Wc, in_idx, out_idx, accum, n, M);

    k3_stats<<<512, 256, 0, stream>>>(accum, ssum, ssq, n);
    k3_final<<<1, 256, 0, stream>>>(ssum, ssq, gamma, beta, scalev, shiftv, n);

    k4_gemm_out<<<rb, 256, 0, stream>>>(accum, W2, b2, x, scalev, shiftv, n);
}